// Round 6
// baseline (93.263 us; speedup 1.0000x reference)
//
#include <hip/hip_runtime.h>
#include <hip/hip_fp16.h>

// total = l1 + 0.5*(1 - mean(ssim3d)), volumes (4,1,128,128,128) f32
// SSIM window 11, zero-padded box sums, /11^3.
// Intermediates (H-sums in LDS, WH-sums in workspace) stored as f16:
// values in [0,121], unbiased RNE rounding, final scalar err ~1e-4 << 1.8e-2.

#define NB 4
#define ND 128
#define NH 128
#define NW 128
#define PLANE (NH * NW)            // 16384
#define VOL (ND * PLANE)           // 2,097,152
#define VOL4 (NB * VOL)            // 8,388,608
#define K1_BLOCKS (NB * ND * 8)    // 4096 (h tiled by 16)
#define K2_BLOCKS 1024             // 8 d-chunks of 16 x 128 (b,h) groups
#define HS_STRIDE 162              // f16; 81 words, 81 % 32 == 17 -> 2-way max

typedef _Float16 half2v __attribute__((ext_vector_type(2)));

// ---------------- Kernel 1: fused W+H box sums of 5 fields + L1 partials ----
// LDS: hs[f][r][c] f16, row stride 162 f16 = 81 words. Stage-B read word =
// 81*ho + 4*wc + j; 81*ho mod 4 takes distinct residues for the 4 ho values
// in a wave -> 4 disjoint groups, each 16 lanes over 8 banks = uniform 2-way
// (free on CDNA4). 25.9 KB -> 6 blocks/CU.
__global__ __launch_bounds__(256) void k_wh(const float* __restrict__ p,
                                            const float* __restrict__ t,
                                            _Float16* __restrict__ S5,
                                            float* __restrict__ l1p,
                                            unsigned int* __restrict__ counter)
{
    __shared__ _Float16 hs[5][16][HS_STRIDE];   // 25,920 B
    __shared__ float red4[4];

    const int bid   = blockIdx.x;
    const int htile = bid & 7;
    const int d     = (bid >> 3) & 127;
    const int b     = bid >> 10;
    const int h0    = htile * 16;
    const int tid   = threadIdx.x;

    if (bid == 0 && tid == 0) *counter = 0;   // reset k2's last-block counter

    // zero the w-halo (logical cols 0..4 and 133..137)
    for (int idx = tid; idx < 5 * 16 * 10; idx += 256) {
        const int f = idx / 160;
        const int rem = idx - f * 160;
        const int r = rem / 10;
        const int c10 = rem - r * 10;
        const int col = (c10 < 5) ? c10 : (128 + c10);
        hs[f][r][col] = (_Float16)0.f;
    }

    // ---- Stage A: H-direction sliding sums (registers) ----
    const int w  = tid & 127;
    const int c  = tid >> 7;          // 0/1: owns output rows hbase..hbase+7
    const int hbase = h0 + c * 8;
    const int pbase = ((b * ND + d) * NH) * NW + w;
    const int wcol = w + 5;

    float rp[11], rt[11];
    float s0 = 0.f, s1 = 0.f, s2 = 0.f, s3 = 0.f, s4 = 0.f;
    float l1_local = 0.f;

#pragma unroll
    for (int i = 0; i < 11; ++i) {
        const int h = hbase - 5 + i;
        float pv = 0.f, tv = 0.f;
        if (h >= 0 && h < NH) {
            pv = p[pbase + h * NW];
            tv = t[pbase + h * NW];
        }
        rp[i] = pv; rt[i] = tv;
        s0 += pv; s1 += tv;
        s2 = fmaf(pv, pv, s2);
        s3 = fmaf(tv, tv, s3);
        s4 = fmaf(pv, tv, s4);
        if (i >= 5) l1_local += fabsf(pv - tv);   // owned rows hbase..hbase+5
    }
    {
        const int r = c * 8;
        hs[0][r][wcol] = (_Float16)s0; hs[1][r][wcol] = (_Float16)s1;
        hs[2][r][wcol] = (_Float16)s2; hs[3][r][wcol] = (_Float16)s3;
        hs[4][r][wcol] = (_Float16)s4;
    }
#pragma unroll
    for (int j = 1; j < 8; ++j) {
        const int h = hbase + j + 5;         // incoming row
        float pv = 0.f, tv = 0.f;
        if (h < NH) {
            pv = p[pbase + h * NW];
            tv = t[pbase + h * NW];
        }
        if (j <= 2) l1_local += fabsf(pv - tv);  // owned rows hbase+6, hbase+7
        const float op = rp[j - 1], ot = rt[j - 1];
        s0 += pv - op;
        s1 += tv - ot;
        s2 += fmaf(pv, pv, -(op * op));
        s3 += fmaf(tv, tv, -(ot * ot));
        s4 += fmaf(pv, tv, -(op * ot));
        rp[j - 1] = pv; rt[j - 1] = tv;
        const int r = c * 8 + j;
        hs[0][r][wcol] = (_Float16)s0; hs[1][r][wcol] = (_Float16)s1;
        hs[2][r][wcol] = (_Float16)s2; hs[3][r][wcol] = (_Float16)s3;
        hs[4][r][wcol] = (_Float16)s4;
    }

    // ---- L1 reduce: in-wave shuffle, one barrier ----
    {
        float v = l1_local;
#pragma unroll
        for (int off = 32; off > 0; off >>= 1) v += __shfl_down(v, off, 64);
        if ((tid & 63) == 0) red4[tid >> 6] = v;
    }
    __syncthreads();          // publishes hs (stage A + halo) and red4
    if (tid == 0) l1p[bid] = red4[0] + red4[1] + red4[2] + red4[3];

    // ---- Stage B: W-direction sliding sums from LDS pairs, f16 stores ----
    const int ho = tid >> 4;          // 0..15
    const int wc = tid & 15;          // owns w in [8*wc, 8*wc+8)
    const size_t obase = (size_t)((b * ND + d) * NH + (h0 + ho)) * NW + wc * 8;

#pragma unroll
    for (int f = 0; f < 5; ++f) {
        float arr[18];
#pragma unroll
        for (int j = 0; j < 9; ++j) {        // 9 x ds_read_b32, 2-way max
            const half2v hv = *(const half2v*)&hs[f][ho][8 * wc + 2 * j];
            arr[2 * j]     = (float)hv[0];
            arr[2 * j + 1] = (float)hv[1];
        }
        float s = 0.f;
#pragma unroll
        for (int j = 0; j < 11; ++j) s += arr[j];
        union { _Float16 h[8]; uint4 u; } o;
        o.h[0] = (_Float16)s;
#pragma unroll
        for (int k = 1; k < 8; ++k) {
            s += arr[10 + k] - arr[k - 1];
            o.h[k] = (_Float16)s;
        }
        *(uint4*)&S5[(size_t)f * VOL4 + obase] = o.u;
    }
    // no trailing barrier: stores drain at endpgm
}

// ---------------- Kernel 2: D-slide + SSIM + reduce + last-block finalize ---
__global__ __launch_bounds__(256) void k_d_ssim(const _Float16* __restrict__ S5,
                                                const float* __restrict__ l1p,
                                                float* __restrict__ ssimp,
                                                unsigned int* __restrict__ counter,
                                                float* __restrict__ out)
{
    __shared__ float red4[4];
    __shared__ bool is_last;
    const float INV = 1.0f / 1331.0f;
    const float C1f = 1e-4f, C2f = 9e-4f;

    const int bid = blockIdx.x;      // 1024 blocks
    const int dc  = bid & 7;         // d chunk (16 deep)
    const int tid = threadIdx.x;
    const int idx = ((bid >> 3) << 8) + tid;   // 0..32767 -> (b,h,wpair)
    const int wp = idx & 63;
    const int h  = (idx >> 6) & 127;
    const int b  = idx >> 13;
    const int d0 = dc * 16;
    const size_t base0 = (size_t)b * VOL + h * NW + wp * 2;

    const _Float16* F0 = S5 + 0 * (size_t)VOL4 + base0;
    const _Float16* F1 = S5 + 1 * (size_t)VOL4 + base0;
    const _Float16* F2 = S5 + 2 * (size_t)VOL4 + base0;
    const _Float16* F3 = S5 + 3 * (size_t)VOL4 + base0;
    const _Float16* F4 = S5 + 4 * (size_t)VOL4 + base0;

#define LOADF(F, dd) (*(const half2v*)&(F)[(size_t)(dd) * PLANE])

    half2v ring[5][11];               // window planes, slot = (plane-(d0-5))%11
    float rsx[5] = {0.f, 0.f, 0.f, 0.f, 0.f};
    float rsy[5] = {0.f, 0.f, 0.f, 0.f, 0.f};

#pragma unroll
    for (int o = -5; o <= 5; ++o) {
        const int dd = d0 + o;
        half2v v0, v1, v2, v3, v4;
        if (dd >= 0 && dd < ND) {
            v0 = LOADF(F0, dd); v1 = LOADF(F1, dd); v2 = LOADF(F2, dd);
            v3 = LOADF(F3, dd); v4 = LOADF(F4, dd);
        } else {
            v0 = v1 = v2 = v3 = v4 = (half2v)(_Float16)0.f;
        }
        ring[0][o + 5] = v0; ring[1][o + 5] = v1; ring[2][o + 5] = v2;
        ring[3][o + 5] = v3; ring[4][o + 5] = v4;
        rsx[0] += (float)v0[0]; rsy[0] += (float)v0[1];
        rsx[1] += (float)v1[0]; rsy[1] += (float)v1[1];
        rsx[2] += (float)v2[0]; rsy[2] += (float)v2[1];
        rsx[3] += (float)v3[0]; rsy[3] += (float)v3[1];
        rsx[4] += (float)v4[0]; rsy[4] += (float)v4[1];
    }

    float acc = 0.f;
#pragma unroll
    for (int s = 0; s < 16; ++s) {
        {
            const float mu_p  = rsx[0] * INV;
            const float mu_t  = rsx[1] * INV;
            const float mu_p2 = mu_p * mu_p;
            const float mu_t2 = mu_t * mu_t;
            const float mu_pt = mu_p * mu_t;
            const float sig_p  = rsx[2] * INV - mu_p2;
            const float sig_t  = rsx[3] * INV - mu_t2;
            const float sig_pt = rsx[4] * INV - mu_pt;
            const float num = (2.f * mu_pt + C1f) * (2.f * sig_pt + C2f);
            const float den = (mu_p2 + mu_t2 + C1f) * (sig_p + sig_t + C2f);
            acc = fmaf(num, __builtin_amdgcn_rcpf(den), acc);
        }
        {
            const float mu_p  = rsy[0] * INV;
            const float mu_t  = rsy[1] * INV;
            const float mu_p2 = mu_p * mu_p;
            const float mu_t2 = mu_t * mu_t;
            const float mu_pt = mu_p * mu_t;
            const float sig_p  = rsy[2] * INV - mu_p2;
            const float sig_t  = rsy[3] * INV - mu_t2;
            const float sig_pt = rsy[4] * INV - mu_pt;
            const float num = (2.f * mu_pt + C1f) * (2.f * sig_pt + C2f);
            const float den = (mu_p2 + mu_t2 + C1f) * (sig_p + sig_t + C2f);
            acc = fmaf(num, __builtin_amdgcn_rcpf(den), acc);
        }

        if (s < 15) {
            const int slot = s % 11;
            const int da = d0 + 6 + s;
            half2v n0, n1, n2, n3, n4;
            if (da < ND) {
                n0 = LOADF(F0, da); n1 = LOADF(F1, da); n2 = LOADF(F2, da);
                n3 = LOADF(F3, da); n4 = LOADF(F4, da);
            } else {
                n0 = n1 = n2 = n3 = n4 = (half2v)(_Float16)0.f;
            }
            rsx[0] += (float)n0[0] - (float)ring[0][slot][0];
            rsy[0] += (float)n0[1] - (float)ring[0][slot][1];
            rsx[1] += (float)n1[0] - (float)ring[1][slot][0];
            rsy[1] += (float)n1[1] - (float)ring[1][slot][1];
            rsx[2] += (float)n2[0] - (float)ring[2][slot][0];
            rsy[2] += (float)n2[1] - (float)ring[2][slot][1];
            rsx[3] += (float)n3[0] - (float)ring[3][slot][0];
            rsy[3] += (float)n3[1] - (float)ring[3][slot][1];
            rsx[4] += (float)n4[0] - (float)ring[4][slot][0];
            rsy[4] += (float)n4[1] - (float)ring[4][slot][1];
            ring[0][slot] = n0; ring[1][slot] = n1; ring[2][slot] = n2;
            ring[3][slot] = n3; ring[4][slot] = n4;
        }
    }
#undef LOADF

    // in-wave shuffle reduce, one barrier
    float v = acc;
#pragma unroll
    for (int off = 32; off > 0; off >>= 1) v += __shfl_down(v, off, 64);
    if ((tid & 63) == 0) red4[tid >> 6] = v;
    __syncthreads();
    if (tid == 0) {
        ssimp[bid] = red4[0] + red4[1] + red4[2] + red4[3];
        __threadfence();                       // publish partial (device scope)
        const unsigned int prev = atomicAdd(counter, 1u);
        is_last = (prev == K2_BLOCKS - 1);
    }
    __syncthreads();

    if (is_last) {
        // final deterministic reduction (double), fixed read order
        __threadfence();
        __shared__ double r1[256];
        __shared__ double r2[256];
        double s1 = 0.0, s2 = 0.0;
        for (int i = tid; i < K1_BLOCKS; i += 256) s1 += (double)l1p[i];
        for (int i = tid; i < K2_BLOCKS; i += 256) s2 += (double)ssimp[i];
        r1[tid] = s1; r2[tid] = s2;
        __syncthreads();
        for (int s = 128; s > 0; s >>= 1) {
            if (tid < s) { r1[tid] += r1[tid + s]; r2[tid] += r2[tid + s]; }
            __syncthreads();
        }
        if (tid == 0) {
            const double N = (double)VOL4;
            const double l1        = r1[0] / N;
            const double ssim_mean = r2[0] / N;
            const double ssim_loss = 1.0 - ssim_mean;
            out[0] = (float)(l1 + 0.5 * ssim_loss);  // total
            out[1] = (float)l1;                      // l1_loss
            out[2] = (float)ssim_loss;               // ssim_loss
            out[3] = 0.f;                            // reg_loss
        }
    }
}

extern "C" void kernel_launch(void* const* d_in, const int* in_sizes, int n_in,
                              void* d_out, int out_size, void* d_ws, size_t ws_size,
                              hipStream_t stream)
{
    const float* pred = (const float*)d_in[0];
    const float* targ = (const float*)d_in[1];
    float* out = (float*)d_out;

    _Float16* S5 = (_Float16*)d_ws;                       // 5*VOL4*2B = 83.9 MB
    float* l1p   = (float*)((char*)d_ws + (size_t)5 * VOL4 * 2);
    float* ssimp = l1p + K1_BLOCKS;
    unsigned int* counter = (unsigned int*)(ssimp + K2_BLOCKS);

    k_wh<<<K1_BLOCKS, 256, 0, stream>>>(pred, targ, S5, l1p, counter);
    k_d_ssim<<<K2_BLOCKS, 256, 0, stream>>>(S5, l1p, ssimp, counter, out);
}

// Round 7
// 67.900 us; speedup vs baseline: 1.3735x; 1.3735x over previous
//
#include <hip/hip_runtime.h>
#include <hip/hip_fp16.h>

// total = l1 + 0.5*(1 - mean(ssim3d)), volumes (4,1,128,128,128) f32
// SSIM window 11, zero-padded box sums, /11^3.
// Intermediates (H-sums in LDS, WH-sums in workspace) stored as f16:
// values in [0,121], unbiased RNE rounding, final scalar err ~1e-4 << 1.8e-2.
//
// NOTE (R6 lesson): do NOT merge the final reduce into k2 via last-block-done.
// The required per-block device-scope __threadfence() flushes the per-XCD L2
// on gfx950 and quadrupled k2's time (17->68 us, FETCH went to HBM).

#define NB 4
#define ND 128
#define NH 128
#define NW 128
#define PLANE (NH * NW)            // 16384
#define VOL (ND * PLANE)           // 2,097,152
#define VOL4 (NB * VOL)            // 8,388,608
#define K1_BLOCKS (NB * ND * 8)    // 4096 (h tiled by 16)
#define K2_BLOCKS 1024             // 8 d-chunks of 16 x 128 (b,h) groups
#define HS_STRIDE 162              // f16; 81 words, 2-way max (see k_wh comment)

typedef _Float16 half2v __attribute__((ext_vector_type(2)));

// ---------------- Kernel 1: fused W+H box sums of 5 fields + L1 partials ----
// LDS: hs[f][r][c] f16, row stride 162 f16 = 81 words. Stage-B read word =
// 81*ho + 4*wc + j; 81*ho mod 4 takes distinct residues for the 4 ho values
// in a wave -> 4 disjoint groups, each 16 lanes over 8 banks = uniform 2-way
// (free on CDNA4). 25.9 KB -> 6 blocks/CU.
__global__ __launch_bounds__(256) void k_wh(const float* __restrict__ p,
                                            const float* __restrict__ t,
                                            _Float16* __restrict__ S5,
                                            float* __restrict__ l1p)
{
    __shared__ _Float16 hs[5][16][HS_STRIDE];   // 25,920 B
    __shared__ float red4[4];

    const int bid   = blockIdx.x;
    const int htile = bid & 7;
    const int d     = (bid >> 3) & 127;
    const int b     = bid >> 10;
    const int h0    = htile * 16;
    const int tid   = threadIdx.x;

    // zero the w-halo (logical cols 0..4 and 133..137)
    for (int idx = tid; idx < 5 * 16 * 10; idx += 256) {
        const int f = idx / 160;
        const int rem = idx - f * 160;
        const int r = rem / 10;
        const int c10 = rem - r * 10;
        const int col = (c10 < 5) ? c10 : (128 + c10);
        hs[f][r][col] = (_Float16)0.f;
    }

    // ---- Stage A: H-direction sliding sums (registers) ----
    const int w  = tid & 127;
    const int c  = tid >> 7;          // 0/1: owns output rows hbase..hbase+7
    const int hbase = h0 + c * 8;
    const int pbase = ((b * ND + d) * NH) * NW + w;
    const int wcol = w + 5;

    float rp[11], rt[11];
    float s0 = 0.f, s1 = 0.f, s2 = 0.f, s3 = 0.f, s4 = 0.f;
    float l1_local = 0.f;

#pragma unroll
    for (int i = 0; i < 11; ++i) {
        const int h = hbase - 5 + i;
        float pv = 0.f, tv = 0.f;
        if (h >= 0 && h < NH) {
            pv = p[pbase + h * NW];
            tv = t[pbase + h * NW];
        }
        rp[i] = pv; rt[i] = tv;
        s0 += pv; s1 += tv;
        s2 = fmaf(pv, pv, s2);
        s3 = fmaf(tv, tv, s3);
        s4 = fmaf(pv, tv, s4);
        if (i >= 5) l1_local += fabsf(pv - tv);   // owned rows hbase..hbase+5
    }
    {
        const int r = c * 8;
        hs[0][r][wcol] = (_Float16)s0; hs[1][r][wcol] = (_Float16)s1;
        hs[2][r][wcol] = (_Float16)s2; hs[3][r][wcol] = (_Float16)s3;
        hs[4][r][wcol] = (_Float16)s4;
    }
#pragma unroll
    for (int j = 1; j < 8; ++j) {
        const int h = hbase + j + 5;         // incoming row
        float pv = 0.f, tv = 0.f;
        if (h < NH) {
            pv = p[pbase + h * NW];
            tv = t[pbase + h * NW];
        }
        if (j <= 2) l1_local += fabsf(pv - tv);  // owned rows hbase+6, hbase+7
        const float op = rp[j - 1], ot = rt[j - 1];
        s0 += pv - op;
        s1 += tv - ot;
        s2 += fmaf(pv, pv, -(op * op));
        s3 += fmaf(tv, tv, -(ot * ot));
        s4 += fmaf(pv, tv, -(op * ot));
        rp[j - 1] = pv; rt[j - 1] = tv;
        const int r = c * 8 + j;
        hs[0][r][wcol] = (_Float16)s0; hs[1][r][wcol] = (_Float16)s1;
        hs[2][r][wcol] = (_Float16)s2; hs[3][r][wcol] = (_Float16)s3;
        hs[4][r][wcol] = (_Float16)s4;
    }

    // ---- L1 reduce: in-wave shuffle, one barrier ----
    {
        float v = l1_local;
#pragma unroll
        for (int off = 32; off > 0; off >>= 1) v += __shfl_down(v, off, 64);
        if ((tid & 63) == 0) red4[tid >> 6] = v;
    }
    __syncthreads();          // publishes hs (stage A + halo) and red4
    if (tid == 0) l1p[bid] = red4[0] + red4[1] + red4[2] + red4[3];

    // ---- Stage B: W-direction sliding sums from LDS pairs, f16 stores ----
    const int ho = tid >> 4;          // 0..15
    const int wc = tid & 15;          // owns w in [8*wc, 8*wc+8)
    const size_t obase = (size_t)((b * ND + d) * NH + (h0 + ho)) * NW + wc * 8;

#pragma unroll
    for (int f = 0; f < 5; ++f) {
        float arr[18];
#pragma unroll
        for (int j = 0; j < 9; ++j) {        // 9 x ds_read_b32, 2-way max
            const half2v hv = *(const half2v*)&hs[f][ho][8 * wc + 2 * j];
            arr[2 * j]     = (float)hv[0];
            arr[2 * j + 1] = (float)hv[1];
        }
        float s = 0.f;
#pragma unroll
        for (int j = 0; j < 11; ++j) s += arr[j];
        union { _Float16 h[8]; uint4 u; } o;
        o.h[0] = (_Float16)s;
#pragma unroll
        for (int k = 1; k < 8; ++k) {
            s += arr[10 + k] - arr[k - 1];
            o.h[k] = (_Float16)s;
        }
        *(uint4*)&S5[(size_t)f * VOL4 + obase] = o.u;
    }
    // no trailing barrier: stores drain at endpgm
}

// ---------------- Kernel 2: D-direction sliding window + SSIM + reduce ------
// Register ring buffer holds the 11-plane window (statically indexed via full
// unroll) -> each plane is LOADED ONCE (no subtract re-loads).
__global__ __launch_bounds__(256) void k_d_ssim(const _Float16* __restrict__ S5,
                                                float* __restrict__ ssimp)
{
    __shared__ float red4[4];
    const float INV = 1.0f / 1331.0f;
    const float C1f = 1e-4f, C2f = 9e-4f;

    const int bid = blockIdx.x;      // 1024 blocks
    const int dc  = bid & 7;         // d chunk (16 deep)
    const int tid = threadIdx.x;
    const int idx = ((bid >> 3) << 8) + tid;   // 0..32767 -> (b,h,wpair)
    const int wp = idx & 63;
    const int h  = (idx >> 6) & 127;
    const int b  = idx >> 13;
    const int d0 = dc * 16;
    const size_t base0 = (size_t)b * VOL + h * NW + wp * 2;

    const _Float16* F0 = S5 + 0 * (size_t)VOL4 + base0;
    const _Float16* F1 = S5 + 1 * (size_t)VOL4 + base0;
    const _Float16* F2 = S5 + 2 * (size_t)VOL4 + base0;
    const _Float16* F3 = S5 + 3 * (size_t)VOL4 + base0;
    const _Float16* F4 = S5 + 4 * (size_t)VOL4 + base0;

#define LOADF(F, dd) (*(const half2v*)&(F)[(size_t)(dd) * PLANE])

    half2v ring[5][11];               // window planes, slot = (plane-(d0-5))%11
    float rsx[5] = {0.f, 0.f, 0.f, 0.f, 0.f};
    float rsy[5] = {0.f, 0.f, 0.f, 0.f, 0.f};

#pragma unroll
    for (int o = -5; o <= 5; ++o) {
        const int dd = d0 + o;
        half2v v0, v1, v2, v3, v4;
        if (dd >= 0 && dd < ND) {
            v0 = LOADF(F0, dd); v1 = LOADF(F1, dd); v2 = LOADF(F2, dd);
            v3 = LOADF(F3, dd); v4 = LOADF(F4, dd);
        } else {
            v0 = v1 = v2 = v3 = v4 = (half2v)(_Float16)0.f;
        }
        ring[0][o + 5] = v0; ring[1][o + 5] = v1; ring[2][o + 5] = v2;
        ring[3][o + 5] = v3; ring[4][o + 5] = v4;
        rsx[0] += (float)v0[0]; rsy[0] += (float)v0[1];
        rsx[1] += (float)v1[0]; rsy[1] += (float)v1[1];
        rsx[2] += (float)v2[0]; rsy[2] += (float)v2[1];
        rsx[3] += (float)v3[0]; rsy[3] += (float)v3[1];
        rsx[4] += (float)v4[0]; rsy[4] += (float)v4[1];
    }

    float acc = 0.f;
#pragma unroll
    for (int s = 0; s < 16; ++s) {
        {
            const float mu_p  = rsx[0] * INV;
            const float mu_t  = rsx[1] * INV;
            const float mu_p2 = mu_p * mu_p;
            const float mu_t2 = mu_t * mu_t;
            const float mu_pt = mu_p * mu_t;
            const float sig_p  = rsx[2] * INV - mu_p2;
            const float sig_t  = rsx[3] * INV - mu_t2;
            const float sig_pt = rsx[4] * INV - mu_pt;
            const float num = (2.f * mu_pt + C1f) * (2.f * sig_pt + C2f);
            const float den = (mu_p2 + mu_t2 + C1f) * (sig_p + sig_t + C2f);
            acc = fmaf(num, __builtin_amdgcn_rcpf(den), acc);
        }
        {
            const float mu_p  = rsy[0] * INV;
            const float mu_t  = rsy[1] * INV;
            const float mu_p2 = mu_p * mu_p;
            const float mu_t2 = mu_t * mu_t;
            const float mu_pt = mu_p * mu_t;
            const float sig_p  = rsy[2] * INV - mu_p2;
            const float sig_t  = rsy[3] * INV - mu_t2;
            const float sig_pt = rsy[4] * INV - mu_pt;
            const float num = (2.f * mu_pt + C1f) * (2.f * sig_pt + C2f);
            const float den = (mu_p2 + mu_t2 + C1f) * (sig_p + sig_t + C2f);
            acc = fmaf(num, __builtin_amdgcn_rcpf(den), acc);
        }

        if (s < 15) {
            const int slot = s % 11;
            const int da = d0 + 6 + s;
            half2v n0, n1, n2, n3, n4;
            if (da < ND) {
                n0 = LOADF(F0, da); n1 = LOADF(F1, da); n2 = LOADF(F2, da);
                n3 = LOADF(F3, da); n4 = LOADF(F4, da);
            } else {
                n0 = n1 = n2 = n3 = n4 = (half2v)(_Float16)0.f;
            }
            rsx[0] += (float)n0[0] - (float)ring[0][slot][0];
            rsy[0] += (float)n0[1] - (float)ring[0][slot][1];
            rsx[1] += (float)n1[0] - (float)ring[1][slot][0];
            rsy[1] += (float)n1[1] - (float)ring[1][slot][1];
            rsx[2] += (float)n2[0] - (float)ring[2][slot][0];
            rsy[2] += (float)n2[1] - (float)ring[2][slot][1];
            rsx[3] += (float)n3[0] - (float)ring[3][slot][0];
            rsy[3] += (float)n3[1] - (float)ring[3][slot][1];
            rsx[4] += (float)n4[0] - (float)ring[4][slot][0];
            rsy[4] += (float)n4[1] - (float)ring[4][slot][1];
            ring[0][slot] = n0; ring[1][slot] = n1; ring[2][slot] = n2;
            ring[3][slot] = n3; ring[4][slot] = n4;
        }
    }
#undef LOADF

    // in-wave shuffle reduce, one barrier
    float v = acc;
#pragma unroll
    for (int off = 32; off > 0; off >>= 1) v += __shfl_down(v, off, 64);
    if ((tid & 63) == 0) red4[tid >> 6] = v;
    __syncthreads();
    if (tid == 0) ssimp[bid] = red4[0] + red4[1] + red4[2] + red4[3];
}

// ---------------- Kernel 3: final deterministic reduction -------------------
__global__ __launch_bounds__(256) void k_final(const float* __restrict__ l1p,
                                               const float* __restrict__ sp,
                                               float* __restrict__ out)
{
    __shared__ double r1[256];
    __shared__ double r2[256];
    const int tid = threadIdx.x;
    double s1 = 0.0, s2 = 0.0;
    for (int i = tid; i < K1_BLOCKS; i += 256) s1 += (double)l1p[i];
    for (int i = tid; i < K2_BLOCKS; i += 256) s2 += (double)sp[i];
    r1[tid] = s1; r2[tid] = s2;
    __syncthreads();
    for (int s = 128; s > 0; s >>= 1) {
        if (tid < s) { r1[tid] += r1[tid + s]; r2[tid] += r2[tid + s]; }
        __syncthreads();
    }
    if (tid == 0) {
        const double N = (double)VOL4;
        const double l1        = r1[0] / N;
        const double ssim_mean = r2[0] / N;
        const double ssim_loss = 1.0 - ssim_mean;
        out[0] = (float)(l1 + 0.5 * ssim_loss);  // total
        out[1] = (float)l1;                      // l1_loss
        out[2] = (float)ssim_loss;               // ssim_loss
        out[3] = 0.f;                            // reg_loss
    }
}

extern "C" void kernel_launch(void* const* d_in, const int* in_sizes, int n_in,
                              void* d_out, int out_size, void* d_ws, size_t ws_size,
                              hipStream_t stream)
{
    const float* pred = (const float*)d_in[0];
    const float* targ = (const float*)d_in[1];
    float* out = (float*)d_out;

    _Float16* S5 = (_Float16*)d_ws;                       // 5*VOL4*2B = 83.9 MB
    float* l1p   = (float*)((char*)d_ws + (size_t)5 * VOL4 * 2);
    float* ssimp = l1p + K1_BLOCKS;

    k_wh<<<K1_BLOCKS, 256, 0, stream>>>(pred, targ, S5, l1p);
    k_d_ssim<<<K2_BLOCKS, 256, 0, stream>>>(S5, ssimp);
    k_final<<<1, 256, 0, stream>>>(l1p, ssimp, out);
}

// Round 8
// 63.802 us; speedup vs baseline: 1.4618x; 1.0642x over previous
//
#include <hip/hip_runtime.h>
#include <hip/hip_fp16.h>

// total = l1 + 0.5*(1 - mean(ssim3d)), volumes (4,1,128,128,128) f32
// SSIM window 11, zero-padded box sums, /11^3.
// Intermediates (H-sums in LDS, WH-sums in workspace) stored as f16:
// values in [0,121], unbiased RNE rounding, final scalar err ~1e-4 << 1.8e-2.
//
// R6 lesson: no last-block-done merge (per-block device __threadfence
// flushes per-XCD L2, quadrupled k2). R7 lesson: k_wh was DS-issue-bound
// (~130 DS ops/thread); this version packs stage-A writes (b32 pairs) and
// uses 2 w-cols/lane -> ~50 DS ops/thread.

#define NB 4
#define ND 128
#define NH 128
#define NW 128
#define PLANE (NH * NW)            // 16384
#define VOL (ND * PLANE)           // 2,097,152
#define VOL4 (NB * VOL)            // 8,388,608
#define K1_BLOCKS (NB * ND * 8)    // 4096 (h tiled by 16)
#define K2_BLOCKS 1024             // 8 d-chunks of 16 x 128 (b,h) groups
#define HS_F16 142                 // f16 row stride = 71 words (odd, 7 mod 32)

typedef _Float16 half2v __attribute__((ext_vector_type(2)));
typedef float f32x2 __attribute__((ext_vector_type(2)));

// ---------------- Kernel 1: fused W+H box sums of 5 fields + L1 partials ----
// Stage A: 4 waves x 4 output rows each, 2 w-cols/lane, float2 loads,
//          keep-first-3 sliding H-sums, packed b32 f16-pair LDS writes.
//          Write word = 71*r + wp + 3: lane-consecutive -> 2-way, free.
// Stage B: 10 b32 reads/field; word = 71*ho + 4*wc + m; 71*ho mod 4 distinct
//          across a wave's 4 ho values -> disjoint bank groups, 2-way, free.
__global__ __launch_bounds__(256) void k_wh(const float* __restrict__ p,
                                            const float* __restrict__ t,
                                            _Float16* __restrict__ S5,
                                            float* __restrict__ l1p)
{
    __shared__ _Float16 hs[5][16][HS_F16];   // 22,720 B
    __shared__ float red4[4];

    const int bid   = blockIdx.x;
    const int htile = bid & 7;
    const int d     = (bid >> 3) & 127;
    const int b     = bid >> 10;
    const int h0    = htile * 16;
    const int tid   = threadIdx.x;

    // zero the w-halo: cols 0..5 (w<0) and 134..141 (w>=128)
    for (int idx = tid; idx < 5 * 16 * 14; idx += 256) {
        const int f = idx / 224;
        const int rem = idx - f * 224;
        const int r = rem / 14;
        const int c14 = rem - r * 14;
        const int col = (c14 < 6) ? c14 : (128 + c14);
        hs[f][r][col] = (_Float16)0.f;
    }

    // ---- Stage A ----
    const int wp = tid & 63;          // lane: owns w = 2*wp, 2*wp+1
    const int c  = tid >> 6;          // wave: owns output rows hbase..hbase+3
    const int hbase = h0 + c * 4;
    const int pbase = ((b * ND + d) * NH) * NW + 2 * wp;
    const int wcol  = 2 * wp + 6;

    const f32x2 z2 = {0.f, 0.f};
    f32x2 sp = z2, st = z2, spp = z2, stt = z2, spt = z2;
    f32x2 kp0 = z2, kp1 = z2, kp2 = z2, kt0 = z2, kt1 = z2, kt2 = z2;
    float l1x = 0.f, l1y = 0.f;

#pragma unroll
    for (int i = 0; i < 11; ++i) {
        const int h = hbase - 5 + i;
        f32x2 pv = z2, tv = z2;
        if (h >= 0 && h < NH) {
            pv = *(const f32x2*)&p[pbase + h * NW];
            tv = *(const f32x2*)&t[pbase + h * NW];
        }
        if (i == 0) { kp0 = pv; kt0 = tv; }
        if (i == 1) { kp1 = pv; kt1 = tv; }
        if (i == 2) { kp2 = pv; kt2 = tv; }
        sp += pv; st += tv;
        spp += pv * pv; stt += tv * tv; spt += pv * tv;
        if (i >= 5 && i <= 8) {      // owned rows hbase..hbase+3: L1 center taps
            l1x += fabsf(pv.x - tv.x);
            l1y += fabsf(pv.y - tv.y);
        }
    }

#define STORE5(r) do {                                                        \
        half2v o_;                                                            \
        o_[0] = (_Float16)sp.x;  o_[1] = (_Float16)sp.y;                      \
        *(half2v*)&hs[0][(r)][wcol] = o_;                                     \
        o_[0] = (_Float16)st.x;  o_[1] = (_Float16)st.y;                      \
        *(half2v*)&hs[1][(r)][wcol] = o_;                                     \
        o_[0] = (_Float16)spp.x; o_[1] = (_Float16)spp.y;                     \
        *(half2v*)&hs[2][(r)][wcol] = o_;                                     \
        o_[0] = (_Float16)stt.x; o_[1] = (_Float16)stt.y;                     \
        *(half2v*)&hs[3][(r)][wcol] = o_;                                     \
        o_[0] = (_Float16)spt.x; o_[1] = (_Float16)spt.y;                     \
        *(half2v*)&hs[4][(r)][wcol] = o_;                                     \
    } while (0)

    STORE5(c * 4);
#pragma unroll
    for (int k = 1; k < 4; ++k) {
        const int h = hbase + 5 + k;         // incoming row
        f32x2 pv = z2, tv = z2;
        if (h < NH) {                        // h >= 6 always
            pv = *(const f32x2*)&p[pbase + h * NW];
            tv = *(const f32x2*)&t[pbase + h * NW];
        }
        const f32x2 op = (k == 1) ? kp0 : ((k == 2) ? kp1 : kp2);
        const f32x2 ot = (k == 1) ? kt0 : ((k == 2) ? kt1 : kt2);
        sp += pv - op;
        st += tv - ot;
        spp += pv * pv - op * op;
        stt += tv * tv - ot * ot;
        spt += pv * tv - op * ot;
        STORE5(c * 4 + k);
    }
#undef STORE5

    // ---- L1 reduce: in-wave shuffle, one barrier ----
    {
        float v = l1x + l1y;
#pragma unroll
        for (int off = 32; off > 0; off >>= 1) v += __shfl_down(v, off, 64);
        if ((tid & 63) == 0) red4[tid >> 6] = v;
    }
    __syncthreads();          // publishes hs (stage A + halo) and red4
    if (tid == 0) l1p[bid] = red4[0] + red4[1] + red4[2] + red4[3];

    // ---- Stage B: W-direction sliding sums from LDS pairs, f16 stores ----
    const int ho = tid >> 4;          // 0..15
    const int wc = tid & 15;          // owns w in [8*wc, 8*wc+8)
    const size_t obase = (size_t)((b * ND + d) * NH + (h0 + ho)) * NW + wc * 8;

#pragma unroll
    for (int f = 0; f < 5; ++f) {
        half2v pr[10];
#pragma unroll
        for (int m = 0; m < 10; ++m)
            pr[m] = *(const half2v*)&hs[f][ho][8 * wc + 2 * m];
        // v[k] = H-sum at w = 8*wc - 5 + k  (halo cols are pre-zeroed)
        float v[18];
#pragma unroll
        for (int k = 0; k < 18; ++k)
            v[k] = (k & 1) ? (float)pr[(k + 1) >> 1][0] : (float)pr[k >> 1][1];
        float s = 0.f;
#pragma unroll
        for (int j = 0; j < 11; ++j) s += v[j];
        union { _Float16 h8[8]; uint4 u; } o;
        o.h8[0] = (_Float16)s;
#pragma unroll
        for (int n = 1; n < 8; ++n) {
            s += v[10 + n] - v[n - 1];
            o.h8[n] = (_Float16)s;
        }
        *(uint4*)&S5[(size_t)f * VOL4 + obase] = o.u;
    }
    // no trailing barrier: stores drain at endpgm
}

// ---------------- Kernel 2: D-direction sliding window + SSIM + reduce ------
// Register ring buffer holds the 11-plane window (statically indexed via full
// unroll) -> each plane is LOADED ONCE (no subtract re-loads).
__global__ __launch_bounds__(256) void k_d_ssim(const _Float16* __restrict__ S5,
                                                float* __restrict__ ssimp)
{
    __shared__ float red4[4];
    const float INV = 1.0f / 1331.0f;
    const float C1f = 1e-4f, C2f = 9e-4f;

    const int bid = blockIdx.x;      // 1024 blocks
    const int dc  = bid & 7;         // d chunk (16 deep)
    const int tid = threadIdx.x;
    const int idx = ((bid >> 3) << 8) + tid;   // 0..32767 -> (b,h,wpair)
    const int wp = idx & 63;
    const int h  = (idx >> 6) & 127;
    const int b  = idx >> 13;
    const int d0 = dc * 16;
    const size_t base0 = (size_t)b * VOL + h * NW + wp * 2;

    const _Float16* F0 = S5 + 0 * (size_t)VOL4 + base0;
    const _Float16* F1 = S5 + 1 * (size_t)VOL4 + base0;
    const _Float16* F2 = S5 + 2 * (size_t)VOL4 + base0;
    const _Float16* F3 = S5 + 3 * (size_t)VOL4 + base0;
    const _Float16* F4 = S5 + 4 * (size_t)VOL4 + base0;

#define LOADF(F, dd) (*(const half2v*)&(F)[(size_t)(dd) * PLANE])

    half2v ring[5][11];               // window planes, slot = (plane-(d0-5))%11
    float rsx[5] = {0.f, 0.f, 0.f, 0.f, 0.f};
    float rsy[5] = {0.f, 0.f, 0.f, 0.f, 0.f};

#pragma unroll
    for (int o = -5; o <= 5; ++o) {
        const int dd = d0 + o;
        half2v v0, v1, v2, v3, v4;
        if (dd >= 0 && dd < ND) {
            v0 = LOADF(F0, dd); v1 = LOADF(F1, dd); v2 = LOADF(F2, dd);
            v3 = LOADF(F3, dd); v4 = LOADF(F4, dd);
        } else {
            v0 = v1 = v2 = v3 = v4 = (half2v)(_Float16)0.f;
        }
        ring[0][o + 5] = v0; ring[1][o + 5] = v1; ring[2][o + 5] = v2;
        ring[3][o + 5] = v3; ring[4][o + 5] = v4;
        rsx[0] += (float)v0[0]; rsy[0] += (float)v0[1];
        rsx[1] += (float)v1[0]; rsy[1] += (float)v1[1];
        rsx[2] += (float)v2[0]; rsy[2] += (float)v2[1];
        rsx[3] += (float)v3[0]; rsy[3] += (float)v3[1];
        rsx[4] += (float)v4[0]; rsy[4] += (float)v4[1];
    }

    float acc = 0.f;
#pragma unroll
    for (int s = 0; s < 16; ++s) {
        {
            const float mu_p  = rsx[0] * INV;
            const float mu_t  = rsx[1] * INV;
            const float mu_p2 = mu_p * mu_p;
            const float mu_t2 = mu_t * mu_t;
            const float mu_pt = mu_p * mu_t;
            const float sig_p  = rsx[2] * INV - mu_p2;
            const float sig_t  = rsx[3] * INV - mu_t2;
            const float sig_pt = rsx[4] * INV - mu_pt;
            const float num = (2.f * mu_pt + C1f) * (2.f * sig_pt + C2f);
            const float den = (mu_p2 + mu_t2 + C1f) * (sig_p + sig_t + C2f);
            acc = fmaf(num, __builtin_amdgcn_rcpf(den), acc);
        }
        {
            const float mu_p  = rsy[0] * INV;
            const float mu_t  = rsy[1] * INV;
            const float mu_p2 = mu_p * mu_p;
            const float mu_t2 = mu_t * mu_t;
            const float mu_pt = mu_p * mu_t;
            const float sig_p  = rsy[2] * INV - mu_p2;
            const float sig_t  = rsy[3] * INV - mu_t2;
            const float sig_pt = rsy[4] * INV - mu_pt;
            const float num = (2.f * mu_pt + C1f) * (2.f * sig_pt + C2f);
            const float den = (mu_p2 + mu_t2 + C1f) * (sig_p + sig_t + C2f);
            acc = fmaf(num, __builtin_amdgcn_rcpf(den), acc);
        }

        if (s < 15) {
            const int slot = s % 11;
            const int da = d0 + 6 + s;
            half2v n0, n1, n2, n3, n4;
            if (da < ND) {
                n0 = LOADF(F0, da); n1 = LOADF(F1, da); n2 = LOADF(F2, da);
                n3 = LOADF(F3, da); n4 = LOADF(F4, da);
            } else {
                n0 = n1 = n2 = n3 = n4 = (half2v)(_Float16)0.f;
            }
            rsx[0] += (float)n0[0] - (float)ring[0][slot][0];
            rsy[0] += (float)n0[1] - (float)ring[0][slot][1];
            rsx[1] += (float)n1[0] - (float)ring[1][slot][0];
            rsy[1] += (float)n1[1] - (float)ring[1][slot][1];
            rsx[2] += (float)n2[0] - (float)ring[2][slot][0];
            rsy[2] += (float)n2[1] - (float)ring[2][slot][1];
            rsx[3] += (float)n3[0] - (float)ring[3][slot][0];
            rsy[3] += (float)n3[1] - (float)ring[3][slot][1];
            rsx[4] += (float)n4[0] - (float)ring[4][slot][0];
            rsy[4] += (float)n4[1] - (float)ring[4][slot][1];
            ring[0][slot] = n0; ring[1][slot] = n1; ring[2][slot] = n2;
            ring[3][slot] = n3; ring[4][slot] = n4;
        }
    }
#undef LOADF

    // in-wave shuffle reduce, one barrier
    float v = acc;
#pragma unroll
    for (int off = 32; off > 0; off >>= 1) v += __shfl_down(v, off, 64);
    if ((tid & 63) == 0) red4[tid >> 6] = v;
    __syncthreads();
    if (tid == 0) ssimp[bid] = red4[0] + red4[1] + red4[2] + red4[3];
}

// ---------------- Kernel 3: final deterministic reduction -------------------
__global__ __launch_bounds__(256) void k_final(const float* __restrict__ l1p,
                                               const float* __restrict__ sp,
                                               float* __restrict__ out)
{
    __shared__ double r1[256];
    __shared__ double r2[256];
    const int tid = threadIdx.x;
    double s1 = 0.0, s2 = 0.0;
    for (int i = tid; i < K1_BLOCKS; i += 256) s1 += (double)l1p[i];
    for (int i = tid; i < K2_BLOCKS; i += 256) s2 += (double)sp[i];
    r1[tid] = s1; r2[tid] = s2;
    __syncthreads();
    for (int s = 128; s > 0; s >>= 1) {
        if (tid < s) { r1[tid] += r1[tid + s]; r2[tid] += r2[tid + s]; }
        __syncthreads();
    }
    if (tid == 0) {
        const double N = (double)VOL4;
        const double l1        = r1[0] / N;
        const double ssim_mean = r2[0] / N;
        const double ssim_loss = 1.0 - ssim_mean;
        out[0] = (float)(l1 + 0.5 * ssim_loss);  // total
        out[1] = (float)l1;                      // l1_loss
        out[2] = (float)ssim_loss;               // ssim_loss
        out[3] = 0.f;                            // reg_loss
    }
}

extern "C" void kernel_launch(void* const* d_in, const int* in_sizes, int n_in,
                              void* d_out, int out_size, void* d_ws, size_t ws_size,
                              hipStream_t stream)
{
    const float* pred = (const float*)d_in[0];
    const float* targ = (const float*)d_in[1];
    float* out = (float*)d_out;

    _Float16* S5 = (_Float16*)d_ws;                       // 5*VOL4*2B = 83.9 MB
    float* l1p   = (float*)((char*)d_ws + (size_t)5 * VOL4 * 2);
    float* ssimp = l1p + K1_BLOCKS;

    k_wh<<<K1_BLOCKS, 256, 0, stream>>>(pred, targ, S5, l1p);
    k_d_ssim<<<K2_BLOCKS, 256, 0, stream>>>(S5, ssimp);
    k_final<<<1, 256, 0, stream>>>(l1p, ssimp, out);
}

// Round 11
// 62.874 us; speedup vs baseline: 1.4833x; 1.0148x over previous
//
#include <hip/hip_runtime.h>
#include <hip/hip_fp16.h>

// total = l1 + 0.5*(1 - mean(ssim3d)), volumes (4,1,128,128,128) f32
// SSIM window 11, zero-padded box sums, /11^3.
// Intermediates (H-sums in LDS, WH-sums in workspace) stored as f16:
// values in [0,121], unbiased RNE rounding, final scalar err ~1e-4 << 1.8e-2.
//
// R6 lesson: no last-block-done merge (per-XCD L2 flush poison).
// R7/R8 lesson: neither barriers nor DS-op count were k_wh's limit; VGPR=40
// showed stage A was load-latency serialized. R9: load the full 14-row
// window into registers UPFRONT (28 independent loads, one wait), compute
// from registers.  (R9/R10 benches lost to infra failures; resubmitting.)

#define NB 4
#define ND 128
#define NH 128
#define NW 128
#define PLANE (NH * NW)            // 16384
#define VOL (ND * PLANE)           // 2,097,152
#define VOL4 (NB * VOL)            // 8,388,608
#define K1_BLOCKS (NB * ND * 8)    // 4096 (h tiled by 16)
#define K2_BLOCKS 1024             // 8 d-chunks of 16 x 128 (b,h) groups
#define HS_F16 142                 // f16 row stride = 71 words (odd, 7 mod 32)

typedef _Float16 half2v __attribute__((ext_vector_type(2)));
typedef float f32x2 __attribute__((ext_vector_type(2)));

// ---------------- Kernel 1: fused W+H box sums of 5 fields + L1 partials ----
// Stage A: 4 waves x 4 output rows each, 2 w-cols/lane. Full 14-row window
//          loaded to registers first (ILP), then 5-field sums, packed b32
//          f16-pair LDS writes (lane-consecutive words -> 2-way, free).
// Stage B: 10 b32 reads/field; word = 71*ho + 4*wc + m; 71*ho mod 4 distinct
//          across a wave's 4 ho values -> disjoint bank groups, 2-way, free.
__global__ __launch_bounds__(256) void k_wh(const float* __restrict__ p,
                                            const float* __restrict__ t,
                                            _Float16* __restrict__ S5,
                                            float* __restrict__ l1p)
{
    __shared__ _Float16 hs[5][16][HS_F16];   // 22,720 B
    __shared__ float red4[4];

    const int bid   = blockIdx.x;
    const int htile = bid & 7;
    const int d     = (bid >> 3) & 127;
    const int b     = bid >> 10;
    const int h0    = htile * 16;
    const int tid   = threadIdx.x;

    // zero the w-halo: cols 0..5 (w<0) and 134..141 (w>=128)
    for (int idx = tid; idx < 5 * 16 * 14; idx += 256) {
        const int f = idx / 224;
        const int rem = idx - f * 224;
        const int r = rem / 14;
        const int c14 = rem - r * 14;
        const int col = (c14 < 6) ? c14 : (128 + c14);
        hs[f][r][col] = (_Float16)0.f;
    }

    // ---- Stage A ----
    const int wp = tid & 63;          // lane: owns w = 2*wp, 2*wp+1
    const int c  = tid >> 6;          // wave: owns output rows hbase..hbase+3
    const int hbase = h0 + c * 4;
    const int pbase = ((b * ND + d) * NH) * NW + 2 * wp;
    const int wcol  = 2 * wp + 6;

    const f32x2 z2 = {0.f, 0.f};

    // Load the whole 14-row window into registers first: 28 independent
    // global_load_dwordx2, issued back-to-back. Guards are wave-uniform.
    f32x2 P[14], T[14];
#pragma unroll
    for (int i = 0; i < 14; ++i) {
        const int h = hbase - 5 + i;
        f32x2 pv = z2, tv = z2;
        if (h >= 0 && h < NH) {
            pv = *(const f32x2*)&p[pbase + h * NW];
            tv = *(const f32x2*)&t[pbase + h * NW];
        }
        P[i] = pv; T[i] = tv;
    }

    // L1 center taps: owned rows hbase..hbase+3 = window idx 5..8
    float l1x = 0.f, l1y = 0.f;
#pragma unroll
    for (int i = 5; i <= 8; ++i) {
        l1x += fabsf(P[i].x - T[i].x);
        l1y += fabsf(P[i].y - T[i].y);
    }

    f32x2 sp = z2, st = z2, spp = z2, stt = z2, spt = z2;
#pragma unroll
    for (int i = 0; i < 11; ++i) {
        const f32x2 pv = P[i], tv = T[i];
        sp += pv; st += tv;
        spp += pv * pv; stt += tv * tv; spt += pv * tv;
    }

#define STORE5(r) do {                                                        \
        half2v o_;                                                            \
        o_[0] = (_Float16)sp.x;  o_[1] = (_Float16)sp.y;                      \
        *(half2v*)&hs[0][(r)][wcol] = o_;                                     \
        o_[0] = (_Float16)st.x;  o_[1] = (_Float16)st.y;                      \
        *(half2v*)&hs[1][(r)][wcol] = o_;                                     \
        o_[0] = (_Float16)spp.x; o_[1] = (_Float16)spp.y;                     \
        *(half2v*)&hs[2][(r)][wcol] = o_;                                     \
        o_[0] = (_Float16)stt.x; o_[1] = (_Float16)stt.y;                     \
        *(half2v*)&hs[3][(r)][wcol] = o_;                                     \
        o_[0] = (_Float16)spt.x; o_[1] = (_Float16)spt.y;                     \
        *(half2v*)&hs[4][(r)][wcol] = o_;                                     \
    } while (0)

    STORE5(c * 4);
#pragma unroll
    for (int k = 1; k < 4; ++k) {
        const f32x2 pv = P[10 + k], tv = T[10 + k];
        const f32x2 op = P[k - 1],  ot = T[k - 1];
        sp += pv - op;
        st += tv - ot;
        spp += pv * pv - op * op;
        stt += tv * tv - ot * ot;
        spt += pv * tv - op * ot;
        STORE5(c * 4 + k);
    }
#undef STORE5

    // ---- L1 reduce: in-wave shuffle, one barrier ----
    {
        float v = l1x + l1y;
#pragma unroll
        for (int off = 32; off > 0; off >>= 1) v += __shfl_down(v, off, 64);
        if ((tid & 63) == 0) red4[tid >> 6] = v;
    }
    __syncthreads();          // publishes hs (stage A + halo) and red4
    if (tid == 0) l1p[bid] = red4[0] + red4[1] + red4[2] + red4[3];

    // ---- Stage B: W-direction sliding sums from LDS pairs, f16 stores ----
    const int ho = tid >> 4;          // 0..15
    const int wc = tid & 15;          // owns w in [8*wc, 8*wc+8)
    const size_t obase = (size_t)((b * ND + d) * NH + (h0 + ho)) * NW + wc * 8;

#pragma unroll
    for (int f = 0; f < 5; ++f) {
        half2v pr[10];
#pragma unroll
        for (int m = 0; m < 10; ++m)
            pr[m] = *(const half2v*)&hs[f][ho][8 * wc + 2 * m];
        // v[k] = H-sum at w = 8*wc - 5 + k  (halo cols are pre-zeroed)
        float v[18];
#pragma unroll
        for (int k = 0; k < 18; ++k)
            v[k] = (k & 1) ? (float)pr[(k + 1) >> 1][0] : (float)pr[k >> 1][1];
        float s = 0.f;
#pragma unroll
        for (int j = 0; j < 11; ++j) s += v[j];
        union { _Float16 h8[8]; uint4 u; } o;
        o.h8[0] = (_Float16)s;
#pragma unroll
        for (int n = 1; n < 8; ++n) {
            s += v[10 + n] - v[n - 1];
            o.h8[n] = (_Float16)s;
        }
        *(uint4*)&S5[(size_t)f * VOL4 + obase] = o.u;
    }
    // no trailing barrier: stores drain at endpgm
}

// ---------------- Kernel 2: D-direction sliding window + SSIM + reduce ------
// Register ring buffer holds the 11-plane window (statically indexed via full
// unroll) -> each plane is LOADED ONCE (no subtract re-loads).
__global__ __launch_bounds__(256) void k_d_ssim(const _Float16* __restrict__ S5,
                                                float* __restrict__ ssimp)
{
    __shared__ float red4[4];
    const float INV = 1.0f / 1331.0f;
    const float C1f = 1e-4f, C2f = 9e-4f;

    const int bid = blockIdx.x;      // 1024 blocks
    const int dc  = bid & 7;         // d chunk (16 deep)
    const int tid = threadIdx.x;
    const int idx = ((bid >> 3) << 8) + tid;   // 0..32767 -> (b,h,wpair)
    const int wp = idx & 63;
    const int h  = (idx >> 6) & 127;
    const int b  = idx >> 13;
    const int d0 = dc * 16;
    const size_t base0 = (size_t)b * VOL + h * NW + wp * 2;

    const _Float16* F0 = S5 + 0 * (size_t)VOL4 + base0;
    const _Float16* F1 = S5 + 1 * (size_t)VOL4 + base0;
    const _Float16* F2 = S5 + 2 * (size_t)VOL4 + base0;
    const _Float16* F3 = S5 + 3 * (size_t)VOL4 + base0;
    const _Float16* F4 = S5 + 4 * (size_t)VOL4 + base0;

#define LOADF(F, dd) (*(const half2v*)&(F)[(size_t)(dd) * PLANE])

    half2v ring[5][11];               // window planes, slot = (plane-(d0-5))%11
    float rsx[5] = {0.f, 0.f, 0.f, 0.f, 0.f};
    float rsy[5] = {0.f, 0.f, 0.f, 0.f, 0.f};

#pragma unroll
    for (int o = -5; o <= 5; ++o) {
        const int dd = d0 + o;
        half2v v0, v1, v2, v3, v4;
        if (dd >= 0 && dd < ND) {
            v0 = LOADF(F0, dd); v1 = LOADF(F1, dd); v2 = LOADF(F2, dd);
            v3 = LOADF(F3, dd); v4 = LOADF(F4, dd);
        } else {
            v0 = v1 = v2 = v3 = v4 = (half2v)(_Float16)0.f;
        }
        ring[0][o + 5] = v0; ring[1][o + 5] = v1; ring[2][o + 5] = v2;
        ring[3][o + 5] = v3; ring[4][o + 5] = v4;
        rsx[0] += (float)v0[0]; rsy[0] += (float)v0[1];
        rsx[1] += (float)v1[0]; rsy[1] += (float)v1[1];
        rsx[2] += (float)v2[0]; rsy[2] += (float)v2[1];
        rsx[3] += (float)v3[0]; rsy[3] += (float)v3[1];
        rsx[4] += (float)v4[0]; rsy[4] += (float)v4[1];
    }

    float acc = 0.f;
#pragma unroll
    for (int s = 0; s < 16; ++s) {
        {
            const float mu_p  = rsx[0] * INV;
            const float mu_t  = rsx[1] * INV;
            const float mu_p2 = mu_p * mu_p;
            const float mu_t2 = mu_t * mu_t;
            const float mu_pt = mu_p * mu_t;
            const float sig_p  = rsx[2] * INV - mu_p2;
            const float sig_t  = rsx[3] * INV - mu_t2;
            const float sig_pt = rsx[4] * INV - mu_pt;
            const float num = (2.f * mu_pt + C1f) * (2.f * sig_pt + C2f);
            const float den = (mu_p2 + mu_t2 + C1f) * (sig_p + sig_t + C2f);
            acc = fmaf(num, __builtin_amdgcn_rcpf(den), acc);
        }
        {
            const float mu_p  = rsy[0] * INV;
            const float mu_t  = rsy[1] * INV;
            const float mu_p2 = mu_p * mu_p;
            const float mu_t2 = mu_t * mu_t;
            const float mu_pt = mu_p * mu_t;
            const float sig_p  = rsy[2] * INV - mu_p2;
            const float sig_t  = rsy[3] * INV - mu_t2;
            const float sig_pt = rsy[4] * INV - mu_pt;
            const float num = (2.f * mu_pt + C1f) * (2.f * sig_pt + C2f);
            const float den = (mu_p2 + mu_t2 + C1f) * (sig_p + sig_t + C2f);
            acc = fmaf(num, __builtin_amdgcn_rcpf(den), acc);
        }

        if (s < 15) {
            const int slot = s % 11;
            const int da = d0 + 6 + s;
            half2v n0, n1, n2, n3, n4;
            if (da < ND) {
                n0 = LOADF(F0, da); n1 = LOADF(F1, da); n2 = LOADF(F2, da);
                n3 = LOADF(F3, da); n4 = LOADF(F4, da);
            } else {
                n0 = n1 = n2 = n3 = n4 = (half2v)(_Float16)0.f;
            }
            rsx[0] += (float)n0[0] - (float)ring[0][slot][0];
            rsy[0] += (float)n0[1] - (float)ring[0][slot][1];
            rsx[1] += (float)n1[0] - (float)ring[1][slot][0];
            rsy[1] += (float)n1[1] - (float)ring[1][slot][1];
            rsx[2] += (float)n2[0] - (float)ring[2][slot][0];
            rsy[2] += (float)n2[1] - (float)ring[2][slot][1];
            rsx[3] += (float)n3[0] - (float)ring[3][slot][0];
            rsy[3] += (float)n3[1] - (float)ring[3][slot][1];
            rsx[4] += (float)n4[0] - (float)ring[4][slot][0];
            rsy[4] += (float)n4[1] - (float)ring[4][slot][1];
            ring[0][slot] = n0; ring[1][slot] = n1; ring[2][slot] = n2;
            ring[3][slot] = n3; ring[4][slot] = n4;
        }
    }
#undef LOADF

    // in-wave shuffle reduce, one barrier
    float v = acc;
#pragma unroll
    for (int off = 32; off > 0; off >>= 1) v += __shfl_down(v, off, 64);
    if ((tid & 63) == 0) red4[tid >> 6] = v;
    __syncthreads();
    if (tid == 0) ssimp[bid] = red4[0] + red4[1] + red4[2] + red4[3];
}

// ---------------- Kernel 3: final deterministic reduction -------------------
__global__ __launch_bounds__(256) void k_final(const float* __restrict__ l1p,
                                               const float* __restrict__ sp,
                                               float* __restrict__ out)
{
    __shared__ double r1[256];
    __shared__ double r2[256];
    const int tid = threadIdx.x;
    double s1 = 0.0, s2 = 0.0;
    for (int i = tid; i < K1_BLOCKS; i += 256) s1 += (double)l1p[i];
    for (int i = tid; i < K2_BLOCKS; i += 256) s2 += (double)sp[i];
    r1[tid] = s1; r2[tid] = s2;
    __syncthreads();
    for (int s = 128; s > 0; s >>= 1) {
        if (tid < s) { r1[tid] += r1[tid + s]; r2[tid] += r2[tid + s]; }
        __syncthreads();
    }
    if (tid == 0) {
        const double N = (double)VOL4;
        const double l1        = r1[0] / N;
        const double ssim_mean = r2[0] / N;
        const double ssim_loss = 1.0 - ssim_mean;
        out[0] = (float)(l1 + 0.5 * ssim_loss);  // total
        out[1] = (float)l1;                      // l1_loss
        out[2] = (float)ssim_loss;               // ssim_loss
        out[3] = 0.f;                            // reg_loss
    }
}

extern "C" void kernel_launch(void* const* d_in, const int* in_sizes, int n_in,
                              void* d_out, int out_size, void* d_ws, size_t ws_size,
                              hipStream_t stream)
{
    const float* pred = (const float*)d_in[0];
    const float* targ = (const float*)d_in[1];
    float* out = (float*)d_out;

    _Float16* S5 = (_Float16*)d_ws;                       // 5*VOL4*2B = 83.9 MB
    float* l1p   = (float*)((char*)d_ws + (size_t)5 * VOL4 * 2);
    float* ssimp = l1p + K1_BLOCKS;

    k_wh<<<K1_BLOCKS, 256, 0, stream>>>(pred, targ, S5, l1p);
    k_d_ssim<<<K2_BLOCKS, 256, 0, stream>>>(S5, ssimp);
    k_final<<<1, 256, 0, stream>>>(l1p, ssimp, out);
}

// Round 12
// 57.554 us; speedup vs baseline: 1.6204x; 1.0924x over previous
//
#include <hip/hip_runtime.h>
#include <hip/hip_fp16.h>

// total = l1 + 0.5*(1 - mean(ssim3d)), volumes (4,1,128,128,128) f32
// SSIM window 11, zero-padded box sums, /11^3.
//
// 4-field formulation: stage A=sum(p+t), D=sum(p-t), U=sum((p+t)^2),
// V=sum((p-t)^2).  Then 2*mu_p*mu_t=(muA^2-muD^2)/2, mu_p^2+mu_t^2=
// (muA^2+muD^2)/2, sig_p+sig_t=(U+V)*INV/2-S2, 2*sig_pt=(U-V)*INV/2-P2.
// f16 intermediates: ranges <= 5324, rel err 4.9e-4, unbiased; final scalar
// err ~1e-4 << 1.8e-2 threshold.
//
// R6: no last-block merge (device fence flushes per-XCD L2: k2 17->68us).
// R11: compiler sinks preloaded loads back (VGPR stayed 40) -> use
// sched_barrier(0) fences to FORCE all 28 loads issued before compute.

#define NB 4
#define ND 128
#define NH 128
#define NW 128
#define PLANE (NH * NW)            // 16384
#define VOL (ND * PLANE)           // 2,097,152
#define VOL4 (NB * VOL)            // 8,388,608
#define K1_BLOCKS (NB * ND * 8)    // 4096 (h tiled by 16)
#define K2_BLOCKS 1024             // 8 d-chunks of 16 x 128 (b,h) groups
#define HS_F16 142                 // f16 row stride = 71 words (odd, 7 mod 32)

typedef _Float16 half2v __attribute__((ext_vector_type(2)));
typedef float f32x2 __attribute__((ext_vector_type(2)));

// ---------------- Kernel 1: fused W+H box sums of 4 fields + L1 partials ----
// Stage A: 4 waves x 4 output rows, 2 w-cols/lane. All 28 window loads issued
//          up front (sched_barrier-pinned), halo-zero DS writes overlap the
//          load flight, then A/D/U/V sums, packed b32 f16-pair LDS writes.
// Stage B: 10 b32 reads/field; word = 71*ho + 4*wc + m; 71*ho mod 4 distinct
//          across a wave's 4 ho values -> disjoint bank groups, 2-way, free.
__global__ __launch_bounds__(256, 4) void k_wh(const float* __restrict__ p,
                                               const float* __restrict__ t,
                                               _Float16* __restrict__ S5,
                                               float* __restrict__ l1p)
{
    __shared__ _Float16 hs[4][16][HS_F16];   // 18,176 B
    __shared__ float red4[4];

    const int bid   = blockIdx.x;
    const int htile = bid & 7;
    const int d     = (bid >> 3) & 127;
    const int b     = bid >> 10;
    const int h0    = htile * 16;
    const int tid   = threadIdx.x;

    // ---- Stage A ----
    const int wp = tid & 63;          // lane: owns w = 2*wp, 2*wp+1
    const int c  = tid >> 6;          // wave: owns output rows hbase..hbase+3
    const int hbase = h0 + c * 4;
    const int pbase = ((b * ND + d) * NH) * NW + 2 * wp;
    const int wcol  = 2 * wp + 6;

    const f32x2 z2 = {0.f, 0.f};

    // Issue ALL 28 window loads first (guards are wave-uniform).
    f32x2 P[14], T[14];
#pragma unroll
    for (int i = 0; i < 14; ++i) {
        const int h = hbase - 5 + i;
        f32x2 pv = z2, tv = z2;
        if (h >= 0 && h < NH) {
            pv = *(const f32x2*)&p[pbase + h * NW];
            tv = *(const f32x2*)&t[pbase + h * NW];
        }
        P[i] = pv; T[i] = tv;
    }
    __builtin_amdgcn_sched_barrier(0);   // loads may not sink below this

    // halo zero (DS writes execute while loads are in flight):
    // cols 0..5 (w<0) and 134..141 (w>=128)
    for (int idx = tid; idx < 4 * 16 * 14; idx += 256) {
        const int f = idx / 224;
        const int rem = idx - f * 224;
        const int r = rem / 14;
        const int c14 = rem - r * 14;
        const int col = (c14 < 6) ? c14 : (128 + c14);
        hs[f][r][col] = (_Float16)0.f;
    }
    __builtin_amdgcn_sched_barrier(0);   // compute may not hoist above

    // Transform to A/D once; P/T die here.
    f32x2 A_[14], D_[14];
#pragma unroll
    for (int i = 0; i < 14; ++i) {
        A_[i] = P[i] + T[i];
        D_[i] = P[i] - T[i];
    }

    // L1 center taps: owned rows hbase..hbase+3 = window idx 5..8
    float l1x = 0.f, l1y = 0.f;
#pragma unroll
    for (int i = 5; i <= 8; ++i) {
        l1x += fabsf(D_[i].x);
        l1y += fabsf(D_[i].y);
    }

    f32x2 sA = z2, sD = z2, sU = z2, sV = z2;
#pragma unroll
    for (int i = 0; i < 11; ++i) {
        const f32x2 a = A_[i], dd = D_[i];
        sA += a; sD += dd;
        sU += a * a; sV += dd * dd;
    }

#define STORE4(r) do {                                                        \
        half2v o_;                                                            \
        o_[0] = (_Float16)sA.x; o_[1] = (_Float16)sA.y;                       \
        *(half2v*)&hs[0][(r)][wcol] = o_;                                     \
        o_[0] = (_Float16)sD.x; o_[1] = (_Float16)sD.y;                       \
        *(half2v*)&hs[1][(r)][wcol] = o_;                                     \
        o_[0] = (_Float16)sU.x; o_[1] = (_Float16)sU.y;                       \
        *(half2v*)&hs[2][(r)][wcol] = o_;                                     \
        o_[0] = (_Float16)sV.x; o_[1] = (_Float16)sV.y;                       \
        *(half2v*)&hs[3][(r)][wcol] = o_;                                     \
    } while (0)

    STORE4(c * 4);
#pragma unroll
    for (int k = 1; k < 4; ++k) {
        const f32x2 an = A_[10 + k], dn = D_[10 + k];
        const f32x2 ao = A_[k - 1],  do_ = D_[k - 1];
        sA += an - ao;
        sD += dn - do_;
        sU += an * an - ao * ao;
        sV += dn * dn - do_ * do_;
        STORE4(c * 4 + k);
    }
#undef STORE4

    // ---- L1 reduce: in-wave shuffle, one barrier ----
    {
        float v = l1x + l1y;
#pragma unroll
        for (int off = 32; off > 0; off >>= 1) v += __shfl_down(v, off, 64);
        if ((tid & 63) == 0) red4[tid >> 6] = v;
    }
    __syncthreads();          // publishes hs (stage A + halo) and red4
    if (tid == 0) l1p[bid] = red4[0] + red4[1] + red4[2] + red4[3];

    // ---- Stage B: W-direction sliding sums from LDS pairs, f16 stores ----
    const int ho = tid >> 4;          // 0..15
    const int wc = tid & 15;          // owns w in [8*wc, 8*wc+8)
    const size_t obase = (size_t)((b * ND + d) * NH + (h0 + ho)) * NW + wc * 8;

#pragma unroll
    for (int f = 0; f < 4; ++f) {
        half2v pr[10];
#pragma unroll
        for (int m = 0; m < 10; ++m)
            pr[m] = *(const half2v*)&hs[f][ho][8 * wc + 2 * m];
        // v[k] = H-sum at w = 8*wc - 5 + k  (halo cols are pre-zeroed)
        float v[18];
#pragma unroll
        for (int k = 0; k < 18; ++k)
            v[k] = (k & 1) ? (float)pr[(k + 1) >> 1][0] : (float)pr[k >> 1][1];
        float s = 0.f;
#pragma unroll
        for (int j = 0; j < 11; ++j) s += v[j];
        union { _Float16 h8[8]; uint4 u; } o;
        o.h8[0] = (_Float16)s;
#pragma unroll
        for (int n = 1; n < 8; ++n) {
            s += v[10 + n] - v[n - 1];
            o.h8[n] = (_Float16)s;
        }
        *(uint4*)&S5[(size_t)f * VOL4 + obase] = o.u;
    }
    // no trailing barrier: stores drain at endpgm
}

// ---------------- Kernel 2: D-direction sliding window + SSIM + reduce ------
// Register ring of the 11-plane window (statically indexed, full unroll).
__global__ __launch_bounds__(256) void k_d_ssim(const _Float16* __restrict__ S5,
                                                float* __restrict__ ssimp)
{
    __shared__ float red4[4];
    const float INV  = 1.0f / 1331.0f;
    const float INV2 = 1.0f / 2662.0f;
    const float C1f = 1e-4f, C2f = 9e-4f;

    const int bid = blockIdx.x;      // 1024 blocks
    const int dc  = bid & 7;         // d chunk (16 deep)
    const int tid = threadIdx.x;
    const int idx = ((bid >> 3) << 8) + tid;   // 0..32767 -> (b,h,wpair)
    const int wp = idx & 63;
    const int h  = (idx >> 6) & 127;
    const int b  = idx >> 13;
    const int d0 = dc * 16;
    const size_t base0 = (size_t)b * VOL + h * NW + wp * 2;

    const _Float16* F0 = S5 + 0 * (size_t)VOL4 + base0;   // A
    const _Float16* F1 = S5 + 1 * (size_t)VOL4 + base0;   // D
    const _Float16* F2 = S5 + 2 * (size_t)VOL4 + base0;   // U
    const _Float16* F3 = S5 + 3 * (size_t)VOL4 + base0;   // V

#define LOADF(F, dd) (*(const half2v*)&(F)[(size_t)(dd) * PLANE])

    half2v ring[4][11];               // window planes, slot = (plane-(d0-5))%11
    float rsx[4] = {0.f, 0.f, 0.f, 0.f};
    float rsy[4] = {0.f, 0.f, 0.f, 0.f};

#pragma unroll
    for (int o = -5; o <= 5; ++o) {
        const int dd = d0 + o;
        half2v v0, v1, v2, v3;
        if (dd >= 0 && dd < ND) {
            v0 = LOADF(F0, dd); v1 = LOADF(F1, dd);
            v2 = LOADF(F2, dd); v3 = LOADF(F3, dd);
        } else {
            v0 = v1 = v2 = v3 = (half2v)(_Float16)0.f;
        }
        ring[0][o + 5] = v0; ring[1][o + 5] = v1;
        ring[2][o + 5] = v2; ring[3][o + 5] = v3;
        rsx[0] += (float)v0[0]; rsy[0] += (float)v0[1];
        rsx[1] += (float)v1[0]; rsy[1] += (float)v1[1];
        rsx[2] += (float)v2[0]; rsy[2] += (float)v2[1];
        rsx[3] += (float)v3[0]; rsy[3] += (float)v3[1];
    }

    float acc = 0.f;
#pragma unroll
    for (int s = 0; s < 16; ++s) {
        {
            const float muA = rsx[0] * INV, muD = rsx[1] * INV;
            const float mAA = muA * muA, mDD = muD * muD;
            const float P2 = 0.5f * (mAA - mDD);     // 2 mu_p mu_t
            const float S2 = 0.5f * (mAA + mDD);     // mu_p^2 + mu_t^2
            const float num = (P2 + C1f) * fmaf(rsx[2] - rsx[3], INV2, C2f - P2);
            const float den = (S2 + C1f) * fmaf(rsx[2] + rsx[3], INV2, C2f - S2);
            acc = fmaf(num, __builtin_amdgcn_rcpf(den), acc);
        }
        {
            const float muA = rsy[0] * INV, muD = rsy[1] * INV;
            const float mAA = muA * muA, mDD = muD * muD;
            const float P2 = 0.5f * (mAA - mDD);
            const float S2 = 0.5f * (mAA + mDD);
            const float num = (P2 + C1f) * fmaf(rsy[2] - rsy[3], INV2, C2f - P2);
            const float den = (S2 + C1f) * fmaf(rsy[2] + rsy[3], INV2, C2f - S2);
            acc = fmaf(num, __builtin_amdgcn_rcpf(den), acc);
        }

        if (s < 15) {
            const int slot = s % 11;
            const int da = d0 + 6 + s;
            half2v n0, n1, n2, n3;
            if (da < ND) {
                n0 = LOADF(F0, da); n1 = LOADF(F1, da);
                n2 = LOADF(F2, da); n3 = LOADF(F3, da);
            } else {
                n0 = n1 = n2 = n3 = (half2v)(_Float16)0.f;
            }
            rsx[0] += (float)n0[0] - (float)ring[0][slot][0];
            rsy[0] += (float)n0[1] - (float)ring[0][slot][1];
            rsx[1] += (float)n1[0] - (float)ring[1][slot][0];
            rsy[1] += (float)n1[1] - (float)ring[1][slot][1];
            rsx[2] += (float)n2[0] - (float)ring[2][slot][0];
            rsy[2] += (float)n2[1] - (float)ring[2][slot][1];
            rsx[3] += (float)n3[0] - (float)ring[3][slot][0];
            rsy[3] += (float)n3[1] - (float)ring[3][slot][1];
            ring[0][slot] = n0; ring[1][slot] = n1;
            ring[2][slot] = n2; ring[3][slot] = n3;
        }
    }
#undef LOADF

    // in-wave shuffle reduce, one barrier
    float v = acc;
#pragma unroll
    for (int off = 32; off > 0; off >>= 1) v += __shfl_down(v, off, 64);
    if ((tid & 63) == 0) red4[tid >> 6] = v;
    __syncthreads();
    if (tid == 0) ssimp[bid] = red4[0] + red4[1] + red4[2] + red4[3];
}

// ---------------- Kernel 3: final deterministic reduction -------------------
__global__ __launch_bounds__(256) void k_final(const float* __restrict__ l1p,
                                               const float* __restrict__ sp,
                                               float* __restrict__ out)
{
    __shared__ double r1[256];
    __shared__ double r2[256];
    const int tid = threadIdx.x;
    double s1 = 0.0, s2 = 0.0;
    for (int i = tid; i < K1_BLOCKS; i += 256) s1 += (double)l1p[i];
    for (int i = tid; i < K2_BLOCKS; i += 256) s2 += (double)sp[i];
    r1[tid] = s1; r2[tid] = s2;
    __syncthreads();
    for (int s = 128; s > 0; s >>= 1) {
        if (tid < s) { r1[tid] += r1[tid + s]; r2[tid] += r2[tid + s]; }
        __syncthreads();
    }
    if (tid == 0) {
        const double N = (double)VOL4;
        const double l1        = r1[0] / N;
        const double ssim_mean = r2[0] / N;
        const double ssim_loss = 1.0 - ssim_mean;
        out[0] = (float)(l1 + 0.5 * ssim_loss);  // total
        out[1] = (float)l1;                      // l1_loss
        out[2] = (float)ssim_loss;               // ssim_loss
        out[3] = 0.f;                            // reg_loss
    }
}

extern "C" void kernel_launch(void* const* d_in, const int* in_sizes, int n_in,
                              void* d_out, int out_size, void* d_ws, size_t ws_size,
                              hipStream_t stream)
{
    const float* pred = (const float*)d_in[0];
    const float* targ = (const float*)d_in[1];
    float* out = (float*)d_out;

    _Float16* S5 = (_Float16*)d_ws;                       // 4*VOL4*2B = 67.1 MB
    float* l1p   = (float*)((char*)d_ws + (size_t)4 * VOL4 * 2);
    float* ssimp = l1p + K1_BLOCKS;

    k_wh<<<K1_BLOCKS, 256, 0, stream>>>(pred, targ, S5, l1p);
    k_d_ssim<<<K2_BLOCKS, 256, 0, stream>>>(S5, ssimp);
    k_final<<<1, 256, 0, stream>>>(l1p, ssimp, out);
}